// Round 3
// baseline (1176.371 us; speedup 1.0000x reference)
//
#include <hip/hip_runtime.h>

#define N_NODES 8192
#define DEG     16
#define NEDGE   (N_NODES*DEG)
#define F       128
#define F3      384
#define RBF     20
#define NLAYER  3
#define NF      (N_NODES*F)
#define PI_F    3.14159265358979f

typedef unsigned short u16;

__device__ __forceinline__ float bf2f(u16 u){ return __uint_as_float(((unsigned)u)<<16); }
__device__ __forceinline__ float silu_f(float x){ return x / (1.f + __expf(-x)); }

// ------------------------------------------------------------ dtype detect
// If rel_dist is bf16, every element is in (0.1, 3.0). If it is fp32, even
// u16 indices are mantissa halfwords (random) -> essentially never all pass.
__global__ void k_detect(const u16* __restrict__ rd, int* __restrict__ flag){
  if (threadIdx.x == 0 && blockIdx.x == 0){
    int ok = 1;
    for (int i = 0; i < 128; i++){
      float v = bf2f(rd[2*i]);
      if (!(v > 0.01f && v < 4.0f)) { ok = 0; break; }
    }
    *flag = ok;   // 1 = inputs are bf16, 0 = inputs are fp32
  }
}

// ---------------------------------------------------- convert input -> f32
__global__ __launch_bounds__(256) void k_cvt(const void* __restrict__ src,
                                             float* __restrict__ dst, int n,
                                             const int* __restrict__ flag){
  int i = blockIdx.x*256 + threadIdx.x;
  if (i >= n) return;
  if (*flag) dst[i] = bf2f(((const u16*)src)[i]);
  else       dst[i] = ((const float*)src)[i];
}

// ---------------------------------------------------------------- init nodes
__global__ __launch_bounds__(256) void k_init(const int* __restrict__ atoms,
                                              const float* __restrict__ emb,
                                              float* __restrict__ s,
                                              float* __restrict__ vA){
  int i = blockIdx.x*256 + threadIdx.x;          // i < NF
  int n = i >> 7, f = i & 127;
  s[i] = emb[atoms[n]*F + f];
  vA[i] = 0.f; vA[NF+i] = 0.f; vA[2*NF+i] = 0.f;
}

// --------------------------------------------------------------- tiled GEMM
// C[M,Ncol] = (flags&2 ? C : 0) + A[M,K] @ B[K,Ncol] (+bias) ; flags&1 -> silu
// A,B,C f32 row-major. M%64==0, Ncol%64==0, K%16==0.
__global__ __launch_bounds__(256) void k_gemm(const float* __restrict__ A,
                                              const float* __restrict__ B,
                                              const float* __restrict__ bias,
                                              float* __restrict__ C,
                                              int M, int Ncol, int K, int flags){
  __shared__ float As[16][68];
  __shared__ float Bs[16][68];
  int t  = threadIdx.x;
  int tx = t & 15, ty = t >> 4;
  int row0 = blockIdx.y << 6, col0 = blockIdx.x << 6;
  float acc[4][4];
  #pragma unroll
  for (int i=0;i<4;i++){ acc[i][0]=0;acc[i][1]=0;acc[i][2]=0;acc[i][3]=0; }

  for (int k0=0;k0<K;k0+=16){
    #pragma unroll
    for (int i=t;i<1024;i+=256){
      int m = i>>4, kk = i&15;
      As[kk][m] = A[(size_t)(row0+m)*K + k0+kk];
    }
    #pragma unroll
    for (int i=t;i<1024;i+=256){
      int kk = i>>6, n = i&63;
      Bs[kk][n] = B[(size_t)(k0+kk)*Ncol + col0+n];
    }
    __syncthreads();
    #pragma unroll
    for (int kk=0;kk<16;kk++){
      float4 av = *(const float4*)&As[kk][ty<<2];
      float4 bv = *(const float4*)&Bs[kk][tx<<2];
      float a0=av.x,a1=av.y,a2=av.z,a3=av.w;
      float b0=bv.x,b1=bv.y,b2=bv.z,b3=bv.w;
      acc[0][0]+=a0*b0; acc[0][1]+=a0*b1; acc[0][2]+=a0*b2; acc[0][3]+=a0*b3;
      acc[1][0]+=a1*b0; acc[1][1]+=a1*b1; acc[1][2]+=a1*b2; acc[1][3]+=a1*b3;
      acc[2][0]+=a2*b0; acc[2][1]+=a2*b1; acc[2][2]+=a2*b2; acc[2][3]+=a2*b3;
      acc[3][0]+=a3*b0; acc[3][1]+=a3*b1; acc[3][2]+=a3*b2; acc[3][3]+=a3*b3;
    }
    __syncthreads();
  }
  #pragma unroll
  for (int i=0;i<4;i++){
    int r = row0 + (ty<<2) + i;
    #pragma unroll
    for (int j=0;j<4;j++){
      int c = col0 + (tx<<2) + j;
      float val = acc[i][j];
      if (flags & 2) val += C[(size_t)r*Ncol + c];
      if (bias)      val += bias[c];
      if (flags & 1) val = silu_f(val);
      C[(size_t)r*Ncol + c] = val;
    }
  }
}

// ------------------------------------------------- fused message aggregation
// One block (128 threads) per destination node n. Its edges are contiguous
// [n*DEG, (n+1)*DEG) because idx_i == repeat(arange(N), DEG); counts == DEG.
// Computes rbf/cut on the fly, W = rbf@rbf_w + rbf_b (rbf_w in LDS), then
// s += mean(p_ss); v_out = v_in + mean(v[j]*p_vv + p_vs*dir).
__global__ __launch_bounds__(128) void k_agg(const int* __restrict__ idx_j,
                                             const float* __restrict__ dist,
                                             const float* __restrict__ dirv,
                                             const float* __restrict__ phi,
                                             const float* __restrict__ rbfw,
                                             const float* __restrict__ rbfb,
                                             const float* __restrict__ v_in,
                                             float* __restrict__ v_out,
                                             float* __restrict__ s){
  __shared__ float rwl[RBF*F3];     // 30 KB
  __shared__ float rbl[F3];
  __shared__ float ed[DEG*24];      // per edge: 20 rbf*cut, cut, dir0..2
  __shared__ int   jl[DEG];
  int t = threadIdx.x;
  int n = blockIdx.x;
  for (int i=t;i<RBF*F3;i+=128) rwl[i] = rbfw[i];
  for (int i=t;i<F3;i+=128)     rbl[i] = rbfb[i];
  for (int i=t;i<DEG*24;i+=128){
    int el = i/24, q = i - el*24;
    int e = n*DEG + el;
    float val;
    if (q <= 20){
      float d = dist[e];
      float cut = 0.5f*(cosf(PI_F*d*(1.f/3.f)) + 1.0f);
      if (q < 20) val = sinf((q+1)*PI_F*d*(1.f/3.f)) * cut / d;
      else        val = cut;
    } else {
      val = dirv[e*3 + (q-21)];
    }
    ed[i] = val;
  }
  if (t < DEG) jl[t] = idx_j[n*DEG + t];
  __syncthreads();

  int f = t;
  float ds=0.f, dv0=0.f, dv1=0.f, dv2=0.f;
  for (int el=0;el<DEG;el++){
    const float* e = &ed[el*24];
    int j = jl[el];
    float cw  = e[20];
    float Wvv = cw*rbl[f], Wss = cw*rbl[F+f], Wvs = cw*rbl[2*F+f];
    #pragma unroll
    for (int r=0;r<RBF;r++){
      float rc = e[r];
      Wvv += rc*rwl[r*F3 + f];
      Wss += rc*rwl[r*F3 + F + f];
      Wvs += rc*rwl[r*F3 + 2*F + f];
    }
    const float* pj = phi + (size_t)j*F3;
    float pvv = Wvv*pj[f], pss = Wss*pj[F+f], pvs = Wvs*pj[2*F+f];
    ds += pss;
    float d0=e[21], d1=e[22], d2=e[23];
    const float* vj = v_in + (size_t)j*F + f;
    dv0 += vj[0]     *pvv + pvs*d0;
    dv1 += vj[NF]    *pvv + pvs*d1;
    dv2 += vj[2*NF]  *pvv + pvs*d2;
  }
  size_t i = (size_t)n*F + f;
  const float inv = 1.f/DEG;
  s[i]          += ds*inv;
  v_out[i]       = v_in[i]      + dv0*inv;
  v_out[NF+i]    = v_in[NF+i]   + dv1*inv;
  v_out[2*NF+i]  = v_in[2*NF+i] + dv2*inv;
}

// ------------------------------------------------------- dot / norm (update)
__global__ __launch_bounds__(256) void k_dotnorm(const float* __restrict__ Uv,
                                                 const float* __restrict__ Vv,
                                                 float* __restrict__ dot,
                                                 float* __restrict__ vnorm){
  int i = blockIdx.x*256 + threadIdx.x;
  float u0=Uv[i], u1=Uv[NF+i], u2=Uv[2*NF+i];
  float w0=Vv[i], w1=Vv[NF+i], w2=Vv[2*NF+i];
  dot[i]   = u0*w0 + u1*w1 + u2*w2;
  vnorm[i] = sqrtf(w0*w0 + w1*w1 + w2*w2);
}

// ------------------------------------------------------------- apply update
__global__ __launch_bounds__(256) void k_apply(const float* __restrict__ a,
                                               const float* __restrict__ dot,
                                               const float* __restrict__ Uv,
                                               float* __restrict__ s,
                                               float* __restrict__ v){
  int i = blockIdx.x*256 + threadIdx.x;
  int n = i >> 7, f = i & 127;
  const float* row = a + (size_t)n*F3;
  float avv = row[f], asv = row[F+f], ass = row[2*F+f];
  s[i] += ass + asv*dot[i];
  v[i]        += Uv[i]*avv;
  v[NF+i]     += Uv[NF+i]*avv;
  v[2*NF+i]   += Uv[2*NF+i]*avv;
}

// ----------------------------------------------------- output (FP32 output)
// d_out layout: s [N,F] flat, then v [N,F,3] flat (row-major), all float32.
__global__ __launch_bounds__(256) void k_pack(const float* __restrict__ s,
                                              const float* __restrict__ v,
                                              float* __restrict__ out){
  int i = blockIdx.x*256 + threadIdx.x;   // i < NF
  out[i] = s[i];
  out[NF + (size_t)i*3 + 0] = v[i];
  out[NF + (size_t)i*3 + 1] = v[NF+i];
  out[NF + (size_t)i*3 + 2] = v[2*NF+i];
}

// ------------------------------------------------------------------ launch
extern "C" void kernel_launch(void* const* d_in, const int* in_sizes, int n_in,
                              void* d_out, int out_size, void* d_ws, size_t ws_size,
                              hipStream_t stream) {
  const int* atoms   = (const int*)d_in[0];
  // d_in[1] = idx_i (== repeat(arange(N),DEG)) -- structure used implicitly
  const int* idxj    = (const int*)d_in[2];

  float* W = (float*)d_ws;
  size_t off = 16;              // first 16 floats reserved for the dtype flag
  int*  flag  = (int*)d_ws;
  float* c_emb = W+off; off += 119*F;
  float* c_dir = W+off; off += NEDGE*3;
  float* c_dst = W+off; off += NEDGE;
  float* c_mw1 = W+off; off += NLAYER*F*F;
  float* c_mb1 = W+off; off += NLAYER*F;
  float* c_mw2 = W+off; off += NLAYER*F*F3;
  float* c_mb2 = W+off; off += NLAYER*F3;
  float* c_rw  = W+off; off += NLAYER*RBF*F3;
  float* c_rb  = W+off; off += NLAYER*F3;
  float* c_Uw  = W+off; off += NLAYER*F*F;
  float* c_Vw  = W+off; off += NLAYER*F*F;
  float* c_w1  = W+off; off += NLAYER*2*F*F;
  float* c_b1  = W+off; off += NLAYER*F;
  float* c_w2  = W+off; off += NLAYER*F*F3;
  float* c_b2  = W+off; off += NLAYER*F3;
  off = (off + 255) & ~(size_t)255;
  float* s    = W+off; off += NF;
  float* vA   = W+off; off += (size_t)3*NF;
  float* vB   = W+off; off += (size_t)3*NF;
  float* phi  = W+off; off += (size_t)3*NF;   // also serves as Vv and 'a'
  float* h    = W+off; off += NF;
  float* Uv   = W+off; off += (size_t)3*NF;
  float* dotb = W+off; off += NF;
  float* vnm  = W+off; off += NF;

  k_detect<<<1, 64, 0, stream>>>((const u16*)d_in[4], flag);
  struct { const void* src; float* dst; int n; } cv[15] = {
    { d_in[5],  c_emb, 119*F },
    { d_in[3],  c_dir, NEDGE*3 },
    { d_in[4],  c_dst, NEDGE },
    { d_in[6],  c_mw1, NLAYER*F*F },
    { d_in[7],  c_mb1, NLAYER*F },
    { d_in[8],  c_mw2, NLAYER*F*F3 },
    { d_in[9],  c_mb2, NLAYER*F3 },
    { d_in[10], c_rw,  NLAYER*RBF*F3 },
    { d_in[11], c_rb,  NLAYER*F3 },
    { d_in[12], c_Uw,  NLAYER*F*F },
    { d_in[13], c_Vw,  NLAYER*F*F },
    { d_in[14], c_w1,  NLAYER*2*F*F },
    { d_in[15], c_b1,  NLAYER*F },
    { d_in[16], c_w2,  NLAYER*F*F3 },
    { d_in[17], c_b2,  NLAYER*F3 },
  };
  for (int i=0;i<15;i++)
    k_cvt<<<(cv[i].n+255)/256, 256, 0, stream>>>(cv[i].src, cv[i].dst, cv[i].n, flag);

  k_init<<<NF/256, 256, 0, stream>>>(atoms, c_emb, s, vA);

  for (int l=0; l<NLAYER; l++){
    float* vin  = (l & 1) ? vB : vA;
    float* vout = (l & 1) ? vA : vB;
    const float* mw1 = c_mw1 + (size_t)l*F*F;
    const float* mb1 = c_mb1 + (size_t)l*F;
    const float* mw2 = c_mw2 + (size_t)l*F*F3;
    const float* mb2 = c_mb2 + (size_t)l*F3;
    const float* rw  = c_rw  + (size_t)l*RBF*F3;
    const float* rb  = c_rb  + (size_t)l*F3;
    const float* uWl = c_Uw  + (size_t)l*F*F;
    const float* vWl = c_Vw  + (size_t)l*F*F;
    const float* w1l = c_w1  + (size_t)l*2*F*F;
    const float* b1l = c_b1  + (size_t)l*F;
    const float* w2l = c_w2  + (size_t)l*F*F3;
    const float* b2l = c_b2  + (size_t)l*F3;

    // ---- message block ----
    k_gemm<<<dim3(F/64,  N_NODES/64), 256, 0, stream>>>(s, mw1, mb1, h,   N_NODES, F,  F, 1);
    k_gemm<<<dim3(F3/64, N_NODES/64), 256, 0, stream>>>(h, mw2, mb2, phi, N_NODES, F3, F, 0);
    k_agg<<<N_NODES, 128, 0, stream>>>(idxj, c_dst, c_dir, phi, rw, rb, vin, vout, s);

    // ---- update block ----  (Vv aliases phi: message phi is dead here)
    float* Vv = phi;
    for (int c=0;c<3;c++){
      k_gemm<<<dim3(F/64, N_NODES/64), 256, 0, stream>>>(vout + (size_t)c*NF, uWl, nullptr,
                                                         Uv + (size_t)c*NF, N_NODES, F, F, 0);
      k_gemm<<<dim3(F/64, N_NODES/64), 256, 0, stream>>>(vout + (size_t)c*NF, vWl, nullptr,
                                                         Vv + (size_t)c*NF, N_NODES, F, F, 0);
    }
    k_dotnorm<<<NF/256, 256, 0, stream>>>(Uv, Vv, dotb, vnm);
    // h = silu([vnorm, s] @ w1 + b1)
    k_gemm<<<dim3(F/64, N_NODES/64), 256, 0, stream>>>(vnm, w1l,       b1l,     h, N_NODES, F, F, 0);
    k_gemm<<<dim3(F/64, N_NODES/64), 256, 0, stream>>>(s,   w1l + F*F, nullptr, h, N_NODES, F, F, 3);
    // a = h @ w2 + b2  (phi buffer again: Vv is dead after dotnorm)
    k_gemm<<<dim3(F3/64, N_NODES/64), 256, 0, stream>>>(h, w2l, b2l, phi, N_NODES, F3, F, 0);
    k_apply<<<NF/256, 256, 0, stream>>>(phi, dotb, Uv, s, vout);
  }

  // after 3 layers the current v buffer is vB
  k_pack<<<NF/256, 256, 0, stream>>>(s, vB, (float*)d_out);
}

// Round 4
// 959.774 us; speedup vs baseline: 1.2257x; 1.2257x over previous
//
#include <hip/hip_runtime.h>

#define N_NODES 8192
#define DEG     16
#define NEDGE   (N_NODES*DEG)
#define F       128
#define F3      384
#define RBF     20
#define NLAYER  3
#define NF      (N_NODES*F)
#define PI_F    3.14159265358979f
#define AGG_G   8      // nodes per k_agg block

typedef unsigned short u16;

__device__ __forceinline__ float bf2f(u16 u){ return __uint_as_float(((unsigned)u)<<16); }
__device__ __forceinline__ float silu_f(float x){ return x / (1.f + __expf(-x)); }

// ------------------------------------------------------------ dtype detect
__global__ void k_detect(const u16* __restrict__ rd, int* __restrict__ flag){
  if (threadIdx.x == 0 && blockIdx.x == 0){
    int ok = 1;
    for (int i = 0; i < 128; i++){
      float v = bf2f(rd[2*i]);
      if (!(v > 0.01f && v < 4.0f)) { ok = 0; break; }
    }
    *flag = ok;   // 1 = inputs are bf16, 0 = inputs are fp32
  }
}

// ---------------------------------------------------- convert input -> f32
__global__ __launch_bounds__(256) void k_cvt(const void* __restrict__ src,
                                             float* __restrict__ dst, int n,
                                             const int* __restrict__ flag){
  int i = blockIdx.x*256 + threadIdx.x;
  if (i >= n) return;
  if (*flag) dst[i] = bf2f(((const u16*)src)[i]);
  else       dst[i] = ((const float*)src)[i];
}

// ------------------------------------- merge Uw|Vw -> [L][128][256] fp32
__global__ __launch_bounds__(256) void k_packUV(const void* __restrict__ Uw,
                                                const void* __restrict__ Vw,
                                                float* __restrict__ out,
                                                const int* __restrict__ flag){
  int i = blockIdx.x*256 + threadIdx.x;      // < NLAYER*F*256
  if (i >= NLAYER*F*256) return;
  int l = i / (F*256); int r = i - l*(F*256); int k = r >> 8; int c = r & 255;
  int src = (l*F + k)*F + (c & 127);
  const void* p = (c < 128) ? Uw : Vw;
  out[i] = (*flag) ? bf2f(((const u16*)p)[src]) : ((const float*)p)[src];
}

// ---------------------------------------------------------------- init nodes
__global__ __launch_bounds__(256) void k_init(const int* __restrict__ atoms,
                                              const float* __restrict__ emb,
                                              float* __restrict__ s,
                                              float* __restrict__ vA){
  int i = blockIdx.x*256 + threadIdx.x;          // i < NF
  int n = i >> 7, f = i & 127;
  s[i] = emb[atoms[n]*F + f];
  vA[i] = 0.f; vA[NF+i] = 0.f; vA[2*NF+i] = 0.f;
}

// --------------------------------------------------------------- tiled GEMM
// C[M,Ncol] = A[M,K] @ B[K,Ncol] (+bias) ; flags&1 -> silu
__global__ __launch_bounds__(256) void k_gemm(const float* __restrict__ A,
                                              const float* __restrict__ B,
                                              const float* __restrict__ bias,
                                              float* __restrict__ C,
                                              int M, int Ncol, int K, int flags){
  __shared__ float As[16][68];
  __shared__ float Bs[16][68];
  int t  = threadIdx.x;
  int tx = t & 15, ty = t >> 4;
  int row0 = blockIdx.y << 6, col0 = blockIdx.x << 6;
  float acc[4][4];
  #pragma unroll
  for (int i=0;i<4;i++){ acc[i][0]=0;acc[i][1]=0;acc[i][2]=0;acc[i][3]=0; }

  for (int k0=0;k0<K;k0+=16){
    #pragma unroll
    for (int i=t;i<1024;i+=256){
      int m = i>>4, kk = i&15;
      As[kk][m] = A[(size_t)(row0+m)*K + k0+kk];
    }
    #pragma unroll
    for (int i=t;i<1024;i+=256){
      int kk = i>>6, n = i&63;
      Bs[kk][n] = B[(size_t)(k0+kk)*Ncol + col0+n];
    }
    __syncthreads();
    #pragma unroll
    for (int kk=0;kk<16;kk++){
      float4 av = *(const float4*)&As[kk][ty<<2];
      float4 bv = *(const float4*)&Bs[kk][tx<<2];
      float a0=av.x,a1=av.y,a2=av.z,a3=av.w;
      float b0=bv.x,b1=bv.y,b2=bv.z,b3=bv.w;
      acc[0][0]+=a0*b0; acc[0][1]+=a0*b1; acc[0][2]+=a0*b2; acc[0][3]+=a0*b3;
      acc[1][0]+=a1*b0; acc[1][1]+=a1*b1; acc[1][2]+=a1*b2; acc[1][3]+=a1*b3;
      acc[2][0]+=a2*b0; acc[2][1]+=a2*b1; acc[2][2]+=a2*b2; acc[2][3]+=a2*b3;
      acc[3][0]+=a3*b0; acc[3][1]+=a3*b1; acc[3][2]+=a3*b2; acc[3][3]+=a3*b3;
    }
    __syncthreads();
  }
  #pragma unroll
  for (int i=0;i<4;i++){
    int r = row0 + (ty<<2) + i;
    #pragma unroll
    for (int j=0;j<4;j++){
      int c = col0 + (tx<<2) + j;
      float val = acc[i][j];
      if (bias)      val += bias[c];
      if (flags & 1) val = silu_f(val);
      C[(size_t)r*Ncol + c] = val;
    }
  }
}

// ------------------------------------------------- fused message aggregation
// 256 threads / AGG_G nodes per block; two nodes in flight (one per half).
// Edges of node n are [n*DEG,(n+1)*DEG) since idx_i == repeat(arange(N),DEG).
__global__ __launch_bounds__(256) void k_agg(const int* __restrict__ idx_j,
                                             const float* __restrict__ dist,
                                             const float* __restrict__ dirv,
                                             const float* __restrict__ phi,
                                             const float* __restrict__ rbfw,
                                             const float* __restrict__ rbfb,
                                             const float* __restrict__ v_in,
                                             float* __restrict__ v_out,
                                             float* __restrict__ s){
  __shared__ float rwl[RBF*F3];     // 30 KB
  __shared__ float rbl[F3];
  __shared__ float ed[2*DEG*24];    // per edge: 20 rbf*cut, cut, dir0..2
  __shared__ int   jl[2*DEG];
  int t = threadIdx.x;
  for (int i=t;i<RBF*F3;i+=256) rwl[i] = rbfw[i];
  for (int i=t;i<F3;i+=256)     rbl[i] = rbfb[i];
  int half = t >> 7, f = t & 127;
  int n0 = blockIdx.x * AGG_G;

  for (int p=0;p<AGG_G/2;p++){
    int nA = n0 + 2*p;
    __syncthreads();               // ed reuse guard (also covers rwl 1st iter)
    for (int i=t;i<2*DEG*24;i+=256){
      int el = i/24, q = i - el*24;
      int e = nA*DEG + el;
      float val;
      if (q <= 20){
        float d = dist[e];
        float cut = 0.5f*(cosf(PI_F*d*(1.f/3.f)) + 1.0f);
        if (q < 20) val = sinf((q+1)*PI_F*d*(1.f/3.f)) * cut / d;
        else        val = cut;
      } else {
        val = dirv[e*3 + (q-21)];
      }
      ed[i] = val;
    }
    if (t < 2*DEG) jl[t] = idx_j[nA*DEG + t];
    __syncthreads();

    int n = nA + half;
    const float* edh = ed + half*DEG*24;
    const int*   jlh = jl + half*DEG;
    float ds=0.f, dv0=0.f, dv1=0.f, dv2=0.f;
    for (int el=0;el<DEG;el++){
      const float* e = &edh[el*24];
      int j = jlh[el];
      float cw  = e[20];
      float Wvv = cw*rbl[f], Wss = cw*rbl[F+f], Wvs = cw*rbl[2*F+f];
      #pragma unroll
      for (int r=0;r<RBF;r++){
        float rc = e[r];
        Wvv += rc*rwl[r*F3 + f];
        Wss += rc*rwl[r*F3 + F + f];
        Wvs += rc*rwl[r*F3 + 2*F + f];
      }
      const float* pj = phi + (size_t)j*F3;
      float pvv = Wvv*pj[f], pss = Wss*pj[F+f], pvs = Wvs*pj[2*F+f];
      ds += pss;
      float d0=e[21], d1=e[22], d2=e[23];
      const float* vj = v_in + (size_t)j*F + f;
      dv0 += vj[0]     *pvv + pvs*d0;
      dv1 += vj[NF]    *pvv + pvs*d1;
      dv2 += vj[2*NF]  *pvv + pvs*d2;
    }
    size_t i = (size_t)n*F + f;
    const float inv = 1.f/DEG;
    s[i]          += ds*inv;
    v_out[i]       = v_in[i]      + dv0*inv;
    v_out[NF+i]    = v_in[NF+i]   + dv1*inv;
    v_out[2*NF+i]  = v_in[2*NF+i] + dv2*inv;
  }
}

// ---------------------------------- dot / norm; builds a_in = [vnorm | s]
// UVv layout: per component c (0..2), [N,256] block at offset c*2NF:
// cols 0..127 = Uv, cols 128..255 = Vv.
__global__ __launch_bounds__(256) void k_dotnorm(const float* __restrict__ UVv,
                                                 const float* __restrict__ s,
                                                 float* __restrict__ dot,
                                                 float* __restrict__ a_in){
  int i = blockIdx.x*256 + threadIdx.x;  // < NF
  int n = i >> 7, f = i & 127;
  size_t b = (size_t)n*256 + f;
  float u0=UVv[b],        w0=UVv[b+128];
  float u1=UVv[2*NF+b],   w1=UVv[2*NF+b+128];
  float u2=UVv[4*NF+b],   w2=UVv[4*NF+b+128];
  dot[i]      = u0*w0 + u1*w1 + u2*w2;
  a_in[b]     = sqrtf(w0*w0 + w1*w1 + w2*w2);
  a_in[b+128] = s[i];
}

// ------------------------------------------------------------- apply update
__global__ __launch_bounds__(256) void k_apply(const float* __restrict__ a,
                                               const float* __restrict__ dot,
                                               const float* __restrict__ UVv,
                                               float* __restrict__ s,
                                               float* __restrict__ v){
  int i = blockIdx.x*256 + threadIdx.x;
  int n = i >> 7, f = i & 127;
  const float* row = a + (size_t)n*F3;
  float avv = row[f], asv = row[F+f], ass = row[2*F+f];
  s[i] += ass + asv*dot[i];
  size_t b = (size_t)n*256 + f;
  v[i]        += UVv[b]*avv;
  v[NF+i]     += UVv[2*NF+b]*avv;
  v[2*NF+i]   += UVv[4*NF+b]*avv;
}

// ----------------------------------------------------- output (FP32 output)
__global__ __launch_bounds__(256) void k_pack(const float* __restrict__ s,
                                              const float* __restrict__ v,
                                              float* __restrict__ out){
  int i = blockIdx.x*256 + threadIdx.x;   // i < NF
  out[i] = s[i];
  out[NF + (size_t)i*3 + 0] = v[i];
  out[NF + (size_t)i*3 + 1] = v[NF+i];
  out[NF + (size_t)i*3 + 2] = v[2*NF+i];
}

// ------------------------------------------------------------------ launch
extern "C" void kernel_launch(void* const* d_in, const int* in_sizes, int n_in,
                              void* d_out, int out_size, void* d_ws, size_t ws_size,
                              hipStream_t stream) {
  const int* atoms   = (const int*)d_in[0];
  const int* idxj    = (const int*)d_in[2];

  float* W = (float*)d_ws;
  size_t off = 16;
  int*  flag  = (int*)d_ws;
  float* c_emb = W+off; off += 119*F;
  float* c_dir = W+off; off += NEDGE*3;
  float* c_dst = W+off; off += NEDGE;
  float* c_mw1 = W+off; off += NLAYER*F*F;
  float* c_mb1 = W+off; off += NLAYER*F;
  float* c_mw2 = W+off; off += NLAYER*F*F3;
  float* c_mb2 = W+off; off += NLAYER*F3;
  float* c_rw  = W+off; off += NLAYER*RBF*F3;
  float* c_rb  = W+off; off += NLAYER*F3;
  float* c_UVw = W+off; off += NLAYER*F*256;
  float* c_w1  = W+off; off += NLAYER*2*F*F;
  float* c_b1  = W+off; off += NLAYER*F;
  float* c_w2  = W+off; off += NLAYER*F*F3;
  float* c_b2  = W+off; off += NLAYER*F3;
  off = (off + 255) & ~(size_t)255;
  float* s    = W+off; off += NF;
  float* vA   = W+off; off += (size_t)3*NF;
  float* vB   = W+off; off += (size_t)3*NF;
  float* UVv  = W+off; off += (size_t)6*NF;   // phi aliases first 3NF
  float* phi  = UVv;
  float* h    = W+off; off += NF;
  float* a_in = W+off; off += (size_t)2*NF;
  float* dotb = W+off; off += NF;

  k_detect<<<1, 64, 0, stream>>>((const u16*)d_in[4], flag);
  struct { const void* src; float* dst; int n; } cv[13] = {
    { d_in[5],  c_emb, 119*F },
    { d_in[3],  c_dir, NEDGE*3 },
    { d_in[4],  c_dst, NEDGE },
    { d_in[6],  c_mw1, NLAYER*F*F },
    { d_in[7],  c_mb1, NLAYER*F },
    { d_in[8],  c_mw2, NLAYER*F*F3 },
    { d_in[9],  c_mb2, NLAYER*F3 },
    { d_in[10], c_rw,  NLAYER*RBF*F3 },
    { d_in[11], c_rb,  NLAYER*F3 },
    { d_in[14], c_w1,  NLAYER*2*F*F },
    { d_in[15], c_b1,  NLAYER*F },
    { d_in[16], c_w2,  NLAYER*F*F3 },
    { d_in[17], c_b2,  NLAYER*F3 },
  };
  for (int i=0;i<13;i++)
    k_cvt<<<(cv[i].n+255)/256, 256, 0, stream>>>(cv[i].src, cv[i].dst, cv[i].n, flag);
  k_packUV<<<(NLAYER*F*256+255)/256, 256, 0, stream>>>(d_in[12], d_in[13], c_UVw, flag);

  k_init<<<NF/256, 256, 0, stream>>>(atoms, c_emb, s, vA);

  for (int l=0; l<NLAYER; l++){
    float* vin  = (l & 1) ? vB : vA;
    float* vout = (l & 1) ? vA : vB;
    const float* mw1 = c_mw1 + (size_t)l*F*F;
    const float* mb1 = c_mb1 + (size_t)l*F;
    const float* mw2 = c_mw2 + (size_t)l*F*F3;
    const float* mb2 = c_mb2 + (size_t)l*F3;
    const float* rw  = c_rw  + (size_t)l*RBF*F3;
    const float* rb  = c_rb  + (size_t)l*F3;
    const float* uvW = c_UVw + (size_t)l*F*256;
    const float* w1l = c_w1  + (size_t)l*2*F*F;
    const float* b1l = c_b1  + (size_t)l*F;
    const float* w2l = c_w2  + (size_t)l*F*F3;
    const float* b2l = c_b2  + (size_t)l*F3;

    // ---- message block ----
    k_gemm<<<dim3(F/64,  N_NODES/64), 256, 0, stream>>>(s, mw1, mb1, h,   N_NODES, F,  F, 1);
    k_gemm<<<dim3(F3/64, N_NODES/64), 256, 0, stream>>>(h, mw2, mb2, phi, N_NODES, F3, F, 0);
    k_agg<<<N_NODES/AGG_G, 256, 0, stream>>>(idxj, c_dst, c_dir, phi, rw, rb, vin, vout, s);

    // ---- update block ----  (UVv overwrites phi: dead after agg)
    for (int c=0;c<3;c++)
      k_gemm<<<dim3(256/64, N_NODES/64), 256, 0, stream>>>(vout + (size_t)c*NF, uvW, nullptr,
                                                           UVv + (size_t)c*2*NF, N_NODES, 256, F, 0);
    k_dotnorm<<<NF/256, 256, 0, stream>>>(UVv, s, dotb, a_in);
    k_gemm<<<dim3(F/64,  N_NODES/64), 256, 0, stream>>>(a_in, w1l, b1l, h, N_NODES, F, 2*F, 1);
    // a = h @ w2 + b2 -> vin buffer (dead)
    k_gemm<<<dim3(F3/64, N_NODES/64), 256, 0, stream>>>(h, w2l, b2l, vin, N_NODES, F3, F, 0);
    k_apply<<<NF/256, 256, 0, stream>>>(vin, dotb, UVv, s, vout);
  }

  k_pack<<<NF/256, 256, 0, stream>>>(s, vB, (float*)d_out);
}

// Round 5
// 697.189 us; speedup vs baseline: 1.6873x; 1.3766x over previous
//
#include <hip/hip_runtime.h>

#define N_NODES 8192
#define DEG     16
#define NEDGE   (N_NODES*DEG)
#define F       128
#define F3      384
#define RBF     20
#define NLAYER  3
#define NF      (N_NODES*F)
#define PI_F    3.14159265358979f
#define AGG_G   8      // nodes per k_agg block

typedef unsigned short u16;
typedef __bf16 bf16x8 __attribute__((ext_vector_type(8)));
typedef float  f32x4  __attribute__((ext_vector_type(4)));

__device__ __forceinline__ float bf2f(u16 u){ return __uint_as_float(((unsigned)u)<<16); }
__device__ __forceinline__ u16 f2bf(float f){
  unsigned x = __float_as_uint(f);
  unsigned r = (x + 0x7FFFu + ((x>>16)&1u)) >> 16;   // RNE
  return (u16)r;
}
__device__ __forceinline__ float lo_bf(unsigned u){ return __uint_as_float(u<<16); }
__device__ __forceinline__ float hi_bf(unsigned u){ return __uint_as_float(u & 0xFFFF0000u); }
__device__ __forceinline__ float silu_f(float x){ return x / (1.f + __expf(-x)); }

// ------------------------------------------------------------ dtype detect
__global__ void k_detect(const u16* __restrict__ rd, int* __restrict__ flag){
  if (threadIdx.x == 0 && blockIdx.x == 0){
    int ok = 1;
    for (int i = 0; i < 128; i++){
      float v = bf2f(rd[2*i]);
      if (!(v > 0.01f && v < 4.0f)) { ok = 0; break; }
    }
    *flag = ok;   // 1 = inputs bf16, 0 = fp32
  }
}

__device__ __forceinline__ float ldsrc(const void* src, int i, int bf){
  return bf ? bf2f(((const u16*)src)[i]) : ((const float*)src)[i];
}

// ---------------------------------------------------- convert input -> f32
__global__ __launch_bounds__(256) void k_cvt(const void* __restrict__ src,
                                             float* __restrict__ dst, int n,
                                             const int* __restrict__ flag){
  int i = blockIdx.x*256 + threadIdx.x;
  if (i >= n) return;
  dst[i] = ldsrc(src, i, *flag);
}

// --------------------- split weight [L][K][N] -> bf16 hi/lo, transposed [L][N][K]
__global__ __launch_bounds__(256) void k_splitW(const void* __restrict__ src,
                                                u16* __restrict__ bth, u16* __restrict__ btl,
                                                int K, int Ncol, int total,
                                                const int* __restrict__ flag){
  int i = blockIdx.x*256 + threadIdx.x;
  if (i >= total) return;
  int kn = K*Ncol; int l = i/kn; int r = i - l*kn; int k = r/Ncol; int n = r - k*Ncol;
  float w = ldsrc(src, i, *flag);
  u16 h = f2bf(w); u16 lo = f2bf(w - bf2f(h));
  size_t o = (size_t)l*kn + (size_t)n*K + k;
  bth[o] = h; btl[o] = lo;
}

// ------------------- merge Uw|Vw [L][F][F]x2 -> transposed split [L][256][F]
__global__ __launch_bounds__(256) void k_splitUV(const void* __restrict__ Uw,
                                                 const void* __restrict__ Vw,
                                                 u16* __restrict__ bth, u16* __restrict__ btl,
                                                 const int* __restrict__ flag){
  int i = blockIdx.x*256 + threadIdx.x;        // out index: [l][n(256)][k(128)]
  if (i >= NLAYER*256*F) return;
  int l = i/(256*F); int r = i - l*(256*F); int n = r>>7; int k = r&127;
  int si = (l*F + k)*F + (n&127);
  float w = ldsrc((n<128)?Uw:Vw, si, *flag);
  u16 h = f2bf(w); u16 lo = f2bf(w - bf2f(h));
  bth[i] = h; btl[i] = lo;
}

// ---------------- pack rbf_w [L][20][F3] -> bf16-pairs [L][10][F3] (u32)
__global__ __launch_bounds__(256) void k_packrbf(const void* __restrict__ src,
                                                 unsigned* __restrict__ out,
                                                 const int* __restrict__ flag){
  int i = blockIdx.x*256 + threadIdx.x;
  if (i >= NLAYER*10*F3) return;
  int l = i/(10*F3); int r = i - l*(10*F3); int r2 = r/F3; int f = r - r2*F3;
  int base = (l*RBF + 2*r2)*F3 + f;
  float w0 = ldsrc(src, base, *flag), w1 = ldsrc(src, base+F3, *flag);
  out[i] = (unsigned)f2bf(w0) | ((unsigned)f2bf(w1)<<16);
}

// ---------------------------------------------------------------- init nodes
__global__ __launch_bounds__(256) void k_init(const int* __restrict__ atoms,
                                              const float* __restrict__ emb,
                                              float* __restrict__ s,
                                              float* __restrict__ vA,
                                              u16* __restrict__ v_bf){
  int i = blockIdx.x*256 + threadIdx.x;          // i < NF
  int n = i >> 7, f = i & 127;
  s[i] = emb[atoms[n]*F + f];
  vA[i] = 0.f; vA[NF+i] = 0.f; vA[2*NF+i] = 0.f;
  v_bf[i] = 0;  v_bf[NF+i] = 0;  v_bf[2*NF+i] = 0;
}

// ------------------------------------------------ split-bf16 MFMA GEMM
// C[M,N] = A[M,K](f32) @ B[K,N] (+bias); B pre-split/transposed bf16 hi/lo [N][K].
// 3-term split (hi*hi + hi*lo + lo*hi) ~ fp32 fidelity.
// flags: 1=silu, 4=also write bf16 C to Cbf, 8=skip f32 C write.
// Tile 64x64, 256 thr = 4 waves, each wave one 32x32 quadrant via 16x16x32 MFMA.
__global__ __launch_bounds__(256) void k_mgemm(const float* __restrict__ A,
                                               const u16* __restrict__ Bh_g,
                                               const u16* __restrict__ Bl_g,
                                               const float* __restrict__ bias,
                                               float* __restrict__ C,
                                               u16* __restrict__ Cbf,
                                               int M, int Ncol, int K, int flags){
  __shared__ u16 Ah[64*40], Al[64*40], Bh[64*40], Bl[64*40];   // 20 KB, row stride 40 (80 B)
  int t = threadIdx.x;
  int row0 = blockIdx.y<<6, col0 = blockIdx.x<<6;
  int sr = t>>2, sc = (t&3)<<3;
  const float* Ag = A + (size_t)(row0+sr)*K + sc;
  const u16* Bgh = Bh_g + (size_t)(col0+sr)*K + sc;
  const u16* Bgl = Bl_g + (size_t)(col0+sr)*K + sc;
  int lane = t&63, w = t>>6;
  int qr = (w>>1)<<5, qc = (w&1)<<5;
  int l15 = lane&15, q8 = (lane>>4)<<3;
  f32x4 acc[2][2];
  #pragma unroll
  for (int mt=0;mt<2;mt++)
    #pragma unroll
    for (int nt=0;nt<2;nt++){ acc[mt][nt][0]=0.f; acc[mt][nt][1]=0.f; acc[mt][nt][2]=0.f; acc[mt][nt][3]=0.f; }

  for (int k0=0;k0<K;k0+=32){
    float4 p0 = *(const float4*)(Ag+k0);
    float4 p1 = *(const float4*)(Ag+k0+4);
    float xs[8] = {p0.x,p0.y,p0.z,p0.w,p1.x,p1.y,p1.z,p1.w};
    unsigned hh[4], ll[4];
    #pragma unroll
    for (int j=0;j<4;j++){
      u16 h0=f2bf(xs[2*j]), h1=f2bf(xs[2*j+1]);
      float l0f = xs[2*j]-bf2f(h0), l1f = xs[2*j+1]-bf2f(h1);
      hh[j] = (unsigned)h0 | ((unsigned)h1<<16);
      ll[j] = (unsigned)f2bf(l0f) | ((unsigned)f2bf(l1f)<<16);
    }
    *(uint4*)&Ah[sr*40+sc] = make_uint4(hh[0],hh[1],hh[2],hh[3]);
    *(uint4*)&Al[sr*40+sc] = make_uint4(ll[0],ll[1],ll[2],ll[3]);
    *(uint4*)&Bh[sr*40+sc] = *(const uint4*)(Bgh+k0);
    *(uint4*)&Bl[sr*40+sc] = *(const uint4*)(Bgl+k0);
    __syncthreads();

    bf16x8 a_h[2], a_l[2], b_h[2], b_l[2];
    #pragma unroll
    for (int mt=0;mt<2;mt++){
      int off = (qr+mt*16+l15)*40 + q8;
      a_h[mt] = *(const bf16x8*)&Ah[off];
      a_l[mt] = *(const bf16x8*)&Al[off];
    }
    #pragma unroll
    for (int nt=0;nt<2;nt++){
      int off = (qc+nt*16+l15)*40 + q8;
      b_h[nt] = *(const bf16x8*)&Bh[off];
      b_l[nt] = *(const bf16x8*)&Bl[off];
    }
    #pragma unroll
    for (int mt=0;mt<2;mt++)
      #pragma unroll
      for (int nt=0;nt<2;nt++){
        acc[mt][nt] = __builtin_amdgcn_mfma_f32_16x16x32_bf16(a_h[mt], b_h[nt], acc[mt][nt], 0,0,0);
        acc[mt][nt] = __builtin_amdgcn_mfma_f32_16x16x32_bf16(a_h[mt], b_l[nt], acc[mt][nt], 0,0,0);
        acc[mt][nt] = __builtin_amdgcn_mfma_f32_16x16x32_bf16(a_l[mt], b_h[nt], acc[mt][nt], 0,0,0);
      }
    __syncthreads();
  }

  int qrow = (lane>>4)<<2;
  #pragma unroll
  for (int mt=0;mt<2;mt++)
    #pragma unroll
    for (int nt=0;nt<2;nt++){
      int gcol = col0 + qc + nt*16 + l15;
      float b = bias ? bias[gcol] : 0.f;
      #pragma unroll
      for (int r=0;r<4;r++){
        int grow = row0 + qr + mt*16 + qrow + r;
        float val = acc[mt][nt][r] + b;
        if (flags & 1) val = silu_f(val);
        size_t o = (size_t)grow*Ncol + gcol;
        if (!(flags & 8)) C[o] = val;
        if (flags & 4)    Cbf[o] = f2bf(val);
      }
    }
}

// ------------------------------------------------- fused message aggregation
// 256 threads / AGG_G nodes; two nodes in flight (one per half-block).
// Gathers phi and v as bf16; rbf_w held in LDS as bf16-pairs.
__global__ __launch_bounds__(256) void k_agg(const int* __restrict__ idx_j,
                                             const float* __restrict__ dist,
                                             const float* __restrict__ dirv,
                                             const u16* __restrict__ phi_bf,
                                             const unsigned* __restrict__ rwp_g,
                                             const float* __restrict__ rbl_g,
                                             const float* __restrict__ v_in,
                                             const u16* __restrict__ v_bf,
                                             float* __restrict__ v_out,
                                             float* __restrict__ s){
  __shared__ unsigned rwp[10*F3];   // 15 KB: bf16 pairs (r even = lo16, r odd = hi16)
  __shared__ float rbl[F3];
  __shared__ float ed[2*DEG*24];    // per edge: 20 rbf*cut, cut, dir0..2
  __shared__ int   jl[2*DEG];
  int t = threadIdx.x;
  for (int i=t;i<10*F3;i+=256) rwp[i] = rwp_g[i];
  for (int i=t;i<F3;i+=256)    rbl[i] = rbl_g[i];
  int half = t >> 7, f = t & 127;
  int n0 = blockIdx.x * AGG_G;

  for (int p=0;p<AGG_G/2;p++){
    int nA = n0 + 2*p;
    __syncthreads();
    for (int i=t;i<2*DEG*24;i+=256){
      int el = i/24, q = i - el*24;
      int e = nA*DEG + el;
      float val;
      if (q <= 20){
        float d = dist[e];
        float cut = 0.5f*(cosf(PI_F*d*(1.f/3.f)) + 1.0f);
        if (q < 20) val = sinf((q+1)*PI_F*d*(1.f/3.f)) * cut / d;
        else        val = cut;
      } else {
        val = dirv[e*3 + (q-21)];
      }
      ed[i] = val;
    }
    if (t < 2*DEG) jl[t] = idx_j[nA*DEG + t];
    __syncthreads();

    int n = nA + half;
    const float* edh = ed + half*DEG*24;
    const int*   jlh = jl + half*DEG;
    float ds=0.f, dv0=0.f, dv1=0.f, dv2=0.f;
    for (int el=0;el<DEG;el++){
      const float* e = &edh[el*24];
      int j = jlh[el];
      float cw  = e[20];
      float Wvv = cw*rbl[f], Wss = cw*rbl[F+f], Wvs = cw*rbl[2*F+f];
      #pragma unroll
      for (int r2=0;r2<10;r2++){
        float rc0 = e[2*r2], rc1 = e[2*r2+1];
        unsigned u0 = rwp[r2*F3 + f];
        unsigned u1 = rwp[r2*F3 + F + f];
        unsigned u2 = rwp[r2*F3 + 2*F + f];
        Wvv += rc0*lo_bf(u0) + rc1*hi_bf(u0);
        Wss += rc0*lo_bf(u1) + rc1*hi_bf(u1);
        Wvs += rc0*lo_bf(u2) + rc1*hi_bf(u2);
      }
      const u16* pj = phi_bf + (size_t)j*F3;
      float pvv = Wvv*bf2f(pj[f]), pss = Wss*bf2f(pj[F+f]), pvs = Wvs*bf2f(pj[2*F+f]);
      ds += pss;
      float d0=e[21], d1=e[22], d2=e[23];
      const u16* vj = v_bf + (size_t)j*F + f;
      dv0 += bf2f(vj[0])    *pvv + pvs*d0;
      dv1 += bf2f(vj[NF])   *pvv + pvs*d1;
      dv2 += bf2f(vj[2*NF]) *pvv + pvs*d2;
    }
    size_t i = (size_t)n*F + f;
    const float inv = 1.f/DEG;
    s[i]          += ds*inv;
    v_out[i]       = v_in[i]      + dv0*inv;
    v_out[NF+i]    = v_in[NF+i]   + dv1*inv;
    v_out[2*NF+i]  = v_in[2*NF+i] + dv2*inv;
  }
}

// ---------------------------------- dot / norm; builds a_in = [vnorm | s]
__global__ __launch_bounds__(256) void k_dotnorm(const float* __restrict__ UVv,
                                                 const float* __restrict__ s,
                                                 float* __restrict__ dot,
                                                 float* __restrict__ a_in){
  int i = blockIdx.x*256 + threadIdx.x;  // < NF
  int n = i >> 7, f = i & 127;
  size_t b = (size_t)n*256 + f;
  float u0=UVv[b],        w0=UVv[b+128];
  float u1=UVv[2*NF+b],   w1=UVv[2*NF+b+128];
  float u2=UVv[4*NF+b],   w2=UVv[4*NF+b+128];
  dot[i]      = u0*w0 + u1*w1 + u2*w2;
  a_in[b]     = sqrtf(w0*w0 + w1*w1 + w2*w2);
  a_in[b+128] = s[i];
}

// ------------------------------------------------------------- apply update
__global__ __launch_bounds__(256) void k_apply(const float* __restrict__ a,
                                               const float* __restrict__ dot,
                                               const float* __restrict__ UVv,
                                               float* __restrict__ s,
                                               float* __restrict__ v,
                                               u16* __restrict__ v_bf){
  int i = blockIdx.x*256 + threadIdx.x;
  int n = i >> 7, f = i & 127;
  const float* row = a + (size_t)n*F3;
  float avv = row[f], asv = row[F+f], ass = row[2*F+f];
  s[i] += ass + asv*dot[i];
  size_t b = (size_t)n*256 + f;
  float nv0 = v[i]      + UVv[b]*avv;
  float nv1 = v[NF+i]   + UVv[2*NF+b]*avv;
  float nv2 = v[2*NF+i] + UVv[4*NF+b]*avv;
  v[i] = nv0; v[NF+i] = nv1; v[2*NF+i] = nv2;
  v_bf[i] = f2bf(nv0); v_bf[NF+i] = f2bf(nv1); v_bf[2*NF+i] = f2bf(nv2);
}

// ----------------------------------------------------- output (FP32 output)
__global__ __launch_bounds__(256) void k_pack(const float* __restrict__ s,
                                              const float* __restrict__ v,
                                              float* __restrict__ out){
  int i = blockIdx.x*256 + threadIdx.x;   // i < NF
  out[i] = s[i];
  out[NF + (size_t)i*3 + 0] = v[i];
  out[NF + (size_t)i*3 + 1] = v[NF+i];
  out[NF + (size_t)i*3 + 2] = v[2*NF+i];
}

// ------------------------------------------------------------------ launch
extern "C" void kernel_launch(void* const* d_in, const int* in_sizes, int n_in,
                              void* d_out, int out_size, void* d_ws, size_t ws_size,
                              hipStream_t stream) {
  const int* atoms   = (const int*)d_in[0];
  const int* idxj    = (const int*)d_in[2];

  float* W = (float*)d_ws;
  size_t off = 16;
  int* flag = (int*)d_ws;
  #define ALLOCF(name, cnt) float* name = W+off; off += (((cnt)+63)&~(size_t)63)
  #define ALLOCU(name, cnt) u16* name = (u16*)(W+off); off += ((((cnt)+1)/2+63)&~(size_t)63)
  ALLOCF(c_emb, 119*F);
  ALLOCF(c_dir, NEDGE*3);
  ALLOCF(c_dst, NEDGE);
  ALLOCF(c_mb1, NLAYER*F);
  ALLOCF(c_mb2, NLAYER*F3);
  ALLOCF(c_rb,  NLAYER*F3);
  ALLOCF(c_b1,  NLAYER*F);
  ALLOCF(c_b2,  NLAYER*F3);
  unsigned* c_rwp = (unsigned*)(W+off); off += ((NLAYER*10*F3+63)&~(size_t)63);
  ALLOCU(w_mw1h, NLAYER*F*F);   ALLOCU(w_mw1l, NLAYER*F*F);
  ALLOCU(w_mw2h, NLAYER*F*F3);  ALLOCU(w_mw2l, NLAYER*F*F3);
  ALLOCU(w_uvh,  NLAYER*256*F); ALLOCU(w_uvl,  NLAYER*256*F);
  ALLOCU(w_w1h,  NLAYER*F*256); ALLOCU(w_w1l,  NLAYER*F*256);
  ALLOCU(w_w2h,  NLAYER*F*F3);  ALLOCU(w_w2l,  NLAYER*F*F3);
  ALLOCU(phi_bf, (size_t)3*NF);
  ALLOCU(v_bf,   (size_t)3*NF);
  ALLOCF(s,    NF);
  ALLOCF(vA,   (size_t)3*NF);
  ALLOCF(vB,   (size_t)3*NF);
  ALLOCF(UVv,  (size_t)6*NF);
  ALLOCF(h,    NF);
  ALLOCF(a_in, (size_t)2*NF);
  ALLOCF(dotb, NF);

  k_detect<<<1, 64, 0, stream>>>((const u16*)d_in[4], flag);
  struct { const void* src; float* dst; int n; } cv[8] = {
    { d_in[5],  c_emb, 119*F },
    { d_in[3],  c_dir, NEDGE*3 },
    { d_in[4],  c_dst, NEDGE },
    { d_in[7],  c_mb1, NLAYER*F },
    { d_in[9],  c_mb2, NLAYER*F3 },
    { d_in[11], c_rb,  NLAYER*F3 },
    { d_in[15], c_b1,  NLAYER*F },
    { d_in[17], c_b2,  NLAYER*F3 },
  };
  for (int i=0;i<8;i++)
    k_cvt<<<(cv[i].n+255)/256, 256, 0, stream>>>(cv[i].src, cv[i].dst, cv[i].n, flag);
  k_splitW<<<(NLAYER*F*F  +255)/256, 256, 0, stream>>>(d_in[6],  w_mw1h, w_mw1l, F,   F,  NLAYER*F*F,   flag);
  k_splitW<<<(NLAYER*F*F3 +255)/256, 256, 0, stream>>>(d_in[8],  w_mw2h, w_mw2l, F,   F3, NLAYER*F*F3,  flag);
  k_splitW<<<(NLAYER*2*F*F+255)/256, 256, 0, stream>>>(d_in[14], w_w1h,  w_w1l,  2*F, F,  NLAYER*2*F*F, flag);
  k_splitW<<<(NLAYER*F*F3 +255)/256, 256, 0, stream>>>(d_in[16], w_w2h,  w_w2l,  F,   F3, NLAYER*F*F3,  flag);
  k_splitUV<<<(NLAYER*256*F+255)/256, 256, 0, stream>>>(d_in[12], d_in[13], w_uvh, w_uvl, flag);
  k_packrbf<<<(NLAYER*10*F3+255)/256, 256, 0, stream>>>(d_in[10], c_rwp, flag);

  k_init<<<NF/256, 256, 0, stream>>>(atoms, c_emb, s, vA, v_bf);

  for (int l=0; l<NLAYER; l++){
    float* vin  = (l & 1) ? vB : vA;
    float* vout = (l & 1) ? vA : vB;
    // ---- message block ----
    k_mgemm<<<dim3(F/64, N_NODES/64), 256, 0, stream>>>(
        s, w_mw1h + (size_t)l*F*F, w_mw1l + (size_t)l*F*F,
        c_mb1 + (size_t)l*F, h, nullptr, N_NODES, F, F, 1);
    k_mgemm<<<dim3(F3/64, N_NODES/64), 256, 0, stream>>>(
        h, w_mw2h + (size_t)l*F*F3, w_mw2l + (size_t)l*F*F3,
        c_mb2 + (size_t)l*F3, nullptr, phi_bf, N_NODES, F3, F, 4|8);
    k_agg<<<N_NODES/AGG_G, 256, 0, stream>>>(
        idxj, c_dst, c_dir, phi_bf, c_rwp + (size_t)l*10*F3, c_rb + (size_t)l*F3,
        vin, v_bf, vout, s);
    // ---- update block ----
    k_mgemm<<<dim3(256/64, 3*N_NODES/64), 256, 0, stream>>>(
        vout, w_uvh + (size_t)l*256*F, w_uvl + (size_t)l*256*F,
        nullptr, UVv, nullptr, 3*N_NODES, 256, F, 0);
    k_dotnorm<<<NF/256, 256, 0, stream>>>(UVv, s, dotb, a_in);
    k_mgemm<<<dim3(F/64, N_NODES/64), 256, 0, stream>>>(
        a_in, w_w1h + (size_t)l*F*256, w_w1l + (size_t)l*F*256,
        c_b1 + (size_t)l*F, h, nullptr, N_NODES, F, 2*F, 1);
    k_mgemm<<<dim3(F3/64, N_NODES/64), 256, 0, stream>>>(
        h, w_w2h + (size_t)l*F*F3, w_w2l + (size_t)l*F*F3,
        c_b2 + (size_t)l*F3, vin, nullptr, N_NODES, F3, F, 0);
    k_apply<<<NF/256, 256, 0, stream>>>(vin, dotb, UVv, s, vout, v_bf);
  }

  k_pack<<<NF/256, 256, 0, stream>>>(s, vB, (float*)d_out);
}

// Round 6
// 527.615 us; speedup vs baseline: 2.2296x; 1.3214x over previous
//
#include <hip/hip_runtime.h>

#define N_NODES 8192
#define DEG     16
#define NEDGE   (N_NODES*DEG)
#define F       128
#define F3      384
#define RBF     20
#define NLAYER  3
#define NF      (N_NODES*F)
#define PI_F    3.14159265358979f
#define AGG_G   8      // nodes per k_agg block

typedef unsigned short u16;
typedef __bf16 bf16x8 __attribute__((ext_vector_type(8)));
typedef float  f32x4  __attribute__((ext_vector_type(4)));

__device__ __forceinline__ float bf2f(u16 u){ return __uint_as_float(((unsigned)u)<<16); }
__device__ __forceinline__ u16 f2bf(float f){
  unsigned x = __float_as_uint(f);
  unsigned r = (x + 0x7FFFu + ((x>>16)&1u)) >> 16;   // RNE
  return (u16)r;
}
__device__ __forceinline__ float lo_bf(unsigned u){ return __uint_as_float(u<<16); }
__device__ __forceinline__ float hi_bf(unsigned u){ return __uint_as_float(u & 0xFFFF0000u); }
__device__ __forceinline__ float silu_f(float x){ return x / (1.f + __expf(-x)); }
__device__ __forceinline__ float ldsrc(const void* src, int i, int bf){
  return bf ? bf2f(((const u16*)src)[i]) : ((const float*)src)[i];
}

// ------------------------------------------------------------ dtype detect
__global__ void k_detect(const u16* __restrict__ rd, int* __restrict__ flag){
  if (threadIdx.x == 0 && blockIdx.x == 0){
    int ok = 1;
    for (int i = 0; i < 128; i++){
      float v = bf2f(rd[2*i]);
      if (!(v > 0.01f && v < 4.0f)) { ok = 0; break; }
    }
    *flag = ok;   // 1 = inputs bf16, 0 = fp32
  }
}

// ------------------------------------------- split helper: [L][K][N] -> [L][N][K] hi/lo
__device__ __forceinline__ void splitw(const void* src, u16* bh, u16* bl,
                                       int i, int K, int Ncol, int bf){
  int kn = K*Ncol; int l = i/kn; int r = i - l*kn; int k = r/Ncol; int n = r - k*Ncol;
  float w = ldsrc(src, i, bf);
  u16 h = f2bf(w);
  size_t o = (size_t)l*kn + (size_t)n*K + k;
  bh[o] = h; bl[o] = f2bf(w - bf2f(h));
}

// -------------------------------------- one fused preamble kernel (all weights)
__global__ __launch_bounds__(256) void k_prep(
    const void* mb1, const void* mb2, const void* rb, const void* b1, const void* b2,
    const void* rw,  const void* mw1, const void* mw2, const void* w1, const void* w2,
    const void* Uw,  const void* Vw,
    float* c_mb1, float* c_mb2, float* c_rb, float* c_b1, float* c_b2, float* c_rw,
    u16* mw1h, u16* mw1l, u16* mw2h, u16* mw2l, u16* w1h, u16* w1l,
    u16* w2h, u16* w2l, u16* uvh, u16* uvl,
    const int* __restrict__ flag){
  int i = blockIdx.x*256 + threadIdx.x;
  int bf = *flag;
  const int S0=NLAYER*F, S1=NLAYER*F3, S2=NLAYER*F3, S3=NLAYER*F, S4=NLAYER*F3;
  const int S5=NLAYER*RBF*F3;
  const int S6=NLAYER*F*F, S7=NLAYER*F*F3, S8=NLAYER*2*F*F, S9=NLAYER*F*F3, S10=NLAYER*256*F;
  if (i < S0){ c_mb1[i]=ldsrc(mb1,i,bf); return; } i-=S0;
  if (i < S1){ c_mb2[i]=ldsrc(mb2,i,bf); return; } i-=S1;
  if (i < S2){ c_rb[i] =ldsrc(rb, i,bf); return; } i-=S2;
  if (i < S3){ c_b1[i] =ldsrc(b1, i,bf); return; } i-=S3;
  if (i < S4){ c_b2[i] =ldsrc(b2, i,bf); return; } i-=S4;
  if (i < S5){ c_rw[i] =ldsrc(rw, i,bf); return; } i-=S5;
  if (i < S6){ splitw(mw1, mw1h, mw1l, i, F,   F,  bf); return; } i-=S6;
  if (i < S7){ splitw(mw2, mw2h, mw2l, i, F,   F3, bf); return; } i-=S7;
  if (i < S8){ splitw(w1,  w1h,  w1l,  i, 2*F, F,  bf); return; } i-=S8;
  if (i < S9){ splitw(w2,  w2h,  w2l,  i, F,   F3, bf); return; } i-=S9;
  if (i < S10){
    int l=i/(256*F); int r=i-l*(256*F); int n=r>>7; int k=r&127;
    int si=(l*F+k)*F+(n&127);
    float w = ldsrc((n<128)?Uw:Vw, si, bf);
    u16 h=f2bf(w); uvh[i]=h; uvl[i]=f2bf(w-bf2f(h));
  }
}
#define PREP_TOTAL (NLAYER*(F+F3+F3+F+F3+RBF*F3+F*F+F*F3+2*F*F+F*F3+256*F))

// ---------------------------------------------------------------- init nodes
__global__ __launch_bounds__(256) void k_init(const int* __restrict__ atoms,
                                              const void* __restrict__ emb_raw,
                                              float* __restrict__ s,
                                              float* __restrict__ vA,
                                              u16* __restrict__ v_pk,
                                              const int* __restrict__ flag){
  int i = blockIdx.x*256 + threadIdx.x;          // i < NF
  int bf = *flag;
  int n = i >> 7, f = i & 127;
  s[i] = ldsrc(emb_raw, atoms[n]*F + f, bf);
  vA[i] = 0.f; vA[NF+i] = 0.f; vA[2*NF+i] = 0.f;
  ((unsigned*)v_pk)[i] = 0;  v_pk[2*(size_t)NF + i] = 0;
}

// ------------------------------------------------ split-bf16 MFMA GEMM
// C[M,N] = A[M,K](f32) @ B[K,N] (+bias); B pre-split/transposed bf16 hi/lo [N][K].
// flags: 1=silu, 4=write packed-bf16 phi to Cbf (vv|ss dwords then vs), 8=skip f32 C.
__global__ __launch_bounds__(256) void k_mgemm(const float* __restrict__ A,
                                               const u16* __restrict__ Bh_g,
                                               const u16* __restrict__ Bl_g,
                                               const float* __restrict__ bias,
                                               float* __restrict__ C,
                                               u16* __restrict__ Cbf,
                                               int M, int Ncol, int K, int flags){
  __shared__ u16 Ah[64*40], Al[64*40], Bh[64*40], Bl[64*40];   // 20 KB
  int t = threadIdx.x;
  int row0 = blockIdx.y<<6, col0 = blockIdx.x<<6;
  int sr = t>>2, sc = (t&3)<<3;
  const float* Ag = A + (size_t)(row0+sr)*K + sc;
  const u16* Bgh = Bh_g + (size_t)(col0+sr)*K + sc;
  const u16* Bgl = Bl_g + (size_t)(col0+sr)*K + sc;
  int lane = t&63, w = t>>6;
  int qr = (w>>1)<<5, qc = (w&1)<<5;
  int l15 = lane&15, q8 = (lane>>4)<<3;
  f32x4 acc[2][2];
  #pragma unroll
  for (int mt=0;mt<2;mt++)
    #pragma unroll
    for (int nt=0;nt<2;nt++){ acc[mt][nt][0]=0.f; acc[mt][nt][1]=0.f; acc[mt][nt][2]=0.f; acc[mt][nt][3]=0.f; }

  for (int k0=0;k0<K;k0+=32){
    float4 p0 = *(const float4*)(Ag+k0);
    float4 p1 = *(const float4*)(Ag+k0+4);
    float xs[8] = {p0.x,p0.y,p0.z,p0.w,p1.x,p1.y,p1.z,p1.w};
    unsigned hh[4], ll[4];
    #pragma unroll
    for (int j=0;j<4;j++){
      u16 h0=f2bf(xs[2*j]), h1=f2bf(xs[2*j+1]);
      float l0f = xs[2*j]-bf2f(h0), l1f = xs[2*j+1]-bf2f(h1);
      hh[j] = (unsigned)h0 | ((unsigned)h1<<16);
      ll[j] = (unsigned)f2bf(l0f) | ((unsigned)f2bf(l1f)<<16);
    }
    *(uint4*)&Ah[sr*40+sc] = make_uint4(hh[0],hh[1],hh[2],hh[3]);
    *(uint4*)&Al[sr*40+sc] = make_uint4(ll[0],ll[1],ll[2],ll[3]);
    *(uint4*)&Bh[sr*40+sc] = *(const uint4*)(Bgh+k0);
    *(uint4*)&Bl[sr*40+sc] = *(const uint4*)(Bgl+k0);
    __syncthreads();

    bf16x8 a_h[2], a_l[2], b_h[2], b_l[2];
    #pragma unroll
    for (int mt=0;mt<2;mt++){
      int off = (qr+mt*16+l15)*40 + q8;
      a_h[mt] = *(const bf16x8*)&Ah[off];
      a_l[mt] = *(const bf16x8*)&Al[off];
    }
    #pragma unroll
    for (int nt=0;nt<2;nt++){
      int off = (qc+nt*16+l15)*40 + q8;
      b_h[nt] = *(const bf16x8*)&Bh[off];
      b_l[nt] = *(const bf16x8*)&Bl[off];
    }
    #pragma unroll
    for (int mt=0;mt<2;mt++)
      #pragma unroll
      for (int nt=0;nt<2;nt++){
        acc[mt][nt] = __builtin_amdgcn_mfma_f32_16x16x32_bf16(a_h[mt], b_h[nt], acc[mt][nt], 0,0,0);
        acc[mt][nt] = __builtin_amdgcn_mfma_f32_16x16x32_bf16(a_h[mt], b_l[nt], acc[mt][nt], 0,0,0);
        acc[mt][nt] = __builtin_amdgcn_mfma_f32_16x16x32_bf16(a_l[mt], b_h[nt], acc[mt][nt], 0,0,0);
      }
    __syncthreads();
  }

  int qrow = (lane>>4)<<2;
  #pragma unroll
  for (int mt=0;mt<2;mt++)
    #pragma unroll
    for (int nt=0;nt<2;nt++){
      int gcol = col0 + qc + nt*16 + l15;
      float b = bias ? bias[gcol] : 0.f;
      #pragma unroll
      for (int r=0;r<4;r++){
        int grow = row0 + qr + mt*16 + qrow + r;
        float val = acc[mt][nt][r] + b;
        if (flags & 1) val = silu_f(val);
        size_t o = (size_t)grow*Ncol + gcol;
        if (!(flags & 8)) C[o] = val;
        if (flags & 4){
          u16 bb = f2bf(val);
          size_t rowo = (size_t)grow*F;
          if (gcol < F)        Cbf[(rowo + gcol)*2]       = bb;   // vv -> lo16
          else if (gcol < 2*F) Cbf[(rowo + gcol - F)*2+1] = bb;   // ss -> hi16
          else                 Cbf[2*(size_t)NF + rowo + gcol - 2*F] = bb; // vs
        }
      }
    }
}

// ------------------------------------------------- fused message aggregation
// 256 threads / AGG_G nodes; two nodes in flight (one per half-block).
// rbf_w columns register-cached; phi/v gathered as packed bf16 (dword+u16).
__global__ __launch_bounds__(256) void k_agg(const int* __restrict__ idx_j,
                                             const void* __restrict__ dist_raw,
                                             const void* __restrict__ dir_raw,
                                             const u16* __restrict__ phi_pk,
                                             const float* __restrict__ rw_g,
                                             const float* __restrict__ rb_g,
                                             const u16* __restrict__ v_pk,
                                             const float* __restrict__ v_in,
                                             float* __restrict__ v_out,
                                             float* __restrict__ s,
                                             const int* __restrict__ flag){
  __shared__ float ed[2*DEG*24];    // per edge: 20 rbf*cut, cut, dir0..2
  __shared__ int   jl[2*DEG];
  int t = threadIdx.x;
  int bf = *flag;
  int half = t >> 7, f = t & 127;

  float rwf[RBF], rws[RBF], rwv[RBF];
  #pragma unroll
  for (int r=0;r<RBF;r++){
    rwf[r] = rw_g[r*F3 + f];
    rws[r] = rw_g[r*F3 + F + f];
    rwv[r] = rw_g[r*F3 + 2*F + f];
  }
  float rb0 = rb_g[f], rb1 = rb_g[F+f], rb2 = rb_g[2*F+f];

  const unsigned* phiA = (const unsigned*)phi_pk;
  const u16*      phiB = phi_pk + 2*(size_t)NF;
  const unsigned* vpA  = (const unsigned*)v_pk;
  const u16*      vpB  = v_pk + 2*(size_t)NF;

  int n0 = blockIdx.x * AGG_G;
  for (int p=0;p<AGG_G/2;p++){
    int nA = n0 + 2*p;
    __syncthreads();
    for (int i=t;i<2*DEG*24;i+=256){
      int el = i/24, q = i - el*24;
      int e = nA*DEG + el;
      float val;
      if (q <= 20){
        float d = ldsrc(dist_raw, e, bf);
        float cut = 0.5f*(cosf(PI_F*d*(1.f/3.f)) + 1.0f);
        if (q < 20) val = sinf((q+1)*PI_F*d*(1.f/3.f)) * cut / d;
        else        val = cut;
      } else {
        val = ldsrc(dir_raw, e*3 + (q-21), bf);
      }
      ed[i] = val;
    }
    if (t < 2*DEG) jl[t] = idx_j[nA*DEG + t];
    __syncthreads();

    int n = nA + half;
    const float* edh = ed + half*DEG*24;
    const int*   jlh = jl + half*DEG;
    float ds=0.f, dv0=0.f, dv1=0.f, dv2=0.f;

    int j0 = jlh[0];
    unsigned pa = phiA[(size_t)j0*F + f];
    u16      pb = phiB[(size_t)j0*F + f];
    unsigned va = vpA [(size_t)j0*F + f];
    u16      vb = vpB [(size_t)j0*F + f];
    for (int el=0;el<DEG;el++){
      unsigned cpa=pa; u16 cpb=pb; unsigned cva=va; u16 cvb=vb;
      if (el+1 < DEG){
        int j1 = jlh[el+1];
        pa = phiA[(size_t)j1*F + f];
        pb = phiB[(size_t)j1*F + f];
        va = vpA [(size_t)j1*F + f];
        vb = vpB [(size_t)j1*F + f];
      }
      const float* e = &edh[el*24];
      float cw = e[20];
      float Wvv = cw*rb0, Wss = cw*rb1, Wvs = cw*rb2;
      #pragma unroll
      for (int r=0;r<RBF;r++){
        float rc = e[r];
        Wvv += rc*rwf[r];
        Wss += rc*rws[r];
        Wvs += rc*rwv[r];
      }
      float pvv = Wvv*lo_bf(cpa), pss = Wss*hi_bf(cpa), pvs = Wvs*bf2f(cpb);
      ds += pss;
      float d0=e[21], d1=e[22], d2=e[23];
      dv0 += lo_bf(cva)*pvv + pvs*d0;
      dv1 += hi_bf(cva)*pvv + pvs*d1;
      dv2 += bf2f(cvb)*pvv + pvs*d2;
    }
    size_t i = (size_t)n*F + f;
    const float inv = 1.f/DEG;
    s[i]          += ds*inv;
    v_out[i]       = v_in[i]      + dv0*inv;
    v_out[NF+i]    = v_in[NF+i]   + dv1*inv;
    v_out[2*NF+i]  = v_in[2*NF+i] + dv2*inv;
  }
}

// ---------------------------------- dot / norm; builds a_in = [vnorm | s]
__global__ __launch_bounds__(256) void k_dotnorm(const float* __restrict__ UVv,
                                                 const float* __restrict__ s,
                                                 float* __restrict__ dot,
                                                 float* __restrict__ a_in){
  int i = blockIdx.x*256 + threadIdx.x;  // < NF
  int n = i >> 7, f = i & 127;
  size_t b = (size_t)n*256 + f;
  float u0=UVv[b],        w0=UVv[b+128];
  float u1=UVv[2*NF+b],   w1=UVv[2*NF+b+128];
  float u2=UVv[4*NF+b],   w2=UVv[4*NF+b+128];
  dot[i]      = u0*w0 + u1*w1 + u2*w2;
  a_in[b]     = sqrtf(w0*w0 + w1*w1 + w2*w2);
  a_in[b+128] = s[i];
}

// ------------------------------------------------------------- apply update
__global__ __launch_bounds__(256) void k_apply(const float* __restrict__ a,
                                               const float* __restrict__ dot,
                                               const float* __restrict__ UVv,
                                               float* __restrict__ s,
                                               float* __restrict__ v,
                                               u16* __restrict__ v_pk){
  int i = blockIdx.x*256 + threadIdx.x;
  int n = i >> 7, f = i & 127;
  const float* row = a + (size_t)n*F3;
  float avv = row[f], asv = row[F+f], ass = row[2*F+f];
  s[i] += ass + asv*dot[i];
  size_t b = (size_t)n*256 + f;
  float nv0 = v[i]      + UVv[b]*avv;
  float nv1 = v[NF+i]   + UVv[2*NF+b]*avv;
  float nv2 = v[2*NF+i] + UVv[4*NF+b]*avv;
  v[i] = nv0; v[NF+i] = nv1; v[2*NF+i] = nv2;
  ((unsigned*)v_pk)[i] = (unsigned)f2bf(nv0) | ((unsigned)f2bf(nv1)<<16);
  v_pk[2*(size_t)NF + i] = f2bf(nv2);
}

// ----------------------------------------------------- output (FP32 output)
__global__ __launch_bounds__(256) void k_pack(const float* __restrict__ s,
                                              const float* __restrict__ v,
                                              float* __restrict__ out){
  int i = blockIdx.x*256 + threadIdx.x;   // i < NF
  out[i] = s[i];
  out[NF + (size_t)i*3 + 0] = v[i];
  out[NF + (size_t)i*3 + 1] = v[NF+i];
  out[NF + (size_t)i*3 + 2] = v[2*NF+i];
}

// ------------------------------------------------------------------ launch
extern "C" void kernel_launch(void* const* d_in, const int* in_sizes, int n_in,
                              void* d_out, int out_size, void* d_ws, size_t ws_size,
                              hipStream_t stream) {
  const int* atoms   = (const int*)d_in[0];
  const int* idxj    = (const int*)d_in[2];

  float* W = (float*)d_ws;
  size_t off = 16;
  int* flag = (int*)d_ws;
  #define ALLOCF(name, cnt) float* name = W+off; off += (((cnt)+63)&~(size_t)63)
  #define ALLOCU(name, cnt) u16* name = (u16*)(W+off); off += ((((cnt)+1)/2+63)&~(size_t)63)
  ALLOCF(c_mb1, NLAYER*F);
  ALLOCF(c_mb2, NLAYER*F3);
  ALLOCF(c_rb,  NLAYER*F3);
  ALLOCF(c_b1,  NLAYER*F);
  ALLOCF(c_b2,  NLAYER*F3);
  ALLOCF(c_rw,  NLAYER*RBF*F3);
  ALLOCU(w_mw1h, NLAYER*F*F);   ALLOCU(w_mw1l, NLAYER*F*F);
  ALLOCU(w_mw2h, NLAYER*F*F3);  ALLOCU(w_mw2l, NLAYER*F*F3);
  ALLOCU(w_uvh,  NLAYER*256*F); ALLOCU(w_uvl,  NLAYER*256*F);
  ALLOCU(w_w1h,  NLAYER*F*256); ALLOCU(w_w1l,  NLAYER*F*256);
  ALLOCU(w_w2h,  NLAYER*F*F3);  ALLOCU(w_w2l,  NLAYER*F*F3);
  ALLOCU(phi_pk, (size_t)3*NF);
  ALLOCU(v_pk,   (size_t)3*NF);
  ALLOCF(s,    NF);
  ALLOCF(vA,   (size_t)3*NF);
  ALLOCF(vB,   (size_t)3*NF);
  ALLOCF(UVv,  (size_t)6*NF);
  ALLOCF(h,    NF);
  ALLOCF(a_in, (size_t)2*NF);
  ALLOCF(dotb, NF);

  k_detect<<<1, 64, 0, stream>>>((const u16*)d_in[4], flag);
  k_prep<<<(PREP_TOTAL+255)/256, 256, 0, stream>>>(
      d_in[7], d_in[9], d_in[11], d_in[15], d_in[17],
      d_in[10], d_in[6], d_in[8], d_in[14], d_in[16],
      d_in[12], d_in[13],
      c_mb1, c_mb2, c_rb, c_b1, c_b2, c_rw,
      w_mw1h, w_mw1l, w_mw2h, w_mw2l, w_w1h, w_w1l,
      w_w2h, w_w2l, w_uvh, w_uvl, flag);

  k_init<<<NF/256, 256, 0, stream>>>(atoms, d_in[5], s, vA, v_pk, flag);

  for (int l=0; l<NLAYER; l++){
    float* vin  = (l & 1) ? vB : vA;
    float* vout = (l & 1) ? vA : vB;
    // ---- message block ----
    k_mgemm<<<dim3(F/64, N_NODES/64), 256, 0, stream>>>(
        s, w_mw1h + (size_t)l*F*F, w_mw1l + (size_t)l*F*F,
        c_mb1 + (size_t)l*F, h, nullptr, N_NODES, F, F, 1);
    k_mgemm<<<dim3(F3/64, N_NODES/64), 256, 0, stream>>>(
        h, w_mw2h + (size_t)l*F*F3, w_mw2l + (size_t)l*F*F3,
        c_mb2 + (size_t)l*F3, nullptr, phi_pk, N_NODES, F3, F, 4|8);
    k_agg<<<N_NODES/AGG_G, 256, 0, stream>>>(
        idxj, d_in[4], d_in[3], phi_pk,
        c_rw + (size_t)l*RBF*F3, c_rb + (size_t)l*F3,
        v_pk, vin, vout, s, flag);
    // ---- update block ----
    k_mgemm<<<dim3(256/64, 3*N_NODES/64), 256, 0, stream>>>(
        vout, w_uvh + (size_t)l*256*F, w_uvl + (size_t)l*256*F,
        nullptr, UVv, nullptr, 3*N_NODES, 256, F, 0);
    k_dotnorm<<<NF/256, 256, 0, stream>>>(UVv, s, dotb, a_in);
    k_mgemm<<<dim3(F/64, N_NODES/64), 256, 0, stream>>>(
        a_in, w_w1h + (size_t)l*F*256, w_w1l + (size_t)l*F*256,
        c_b1 + (size_t)l*F, h, nullptr, N_NODES, F, 2*F, 1);
    k_mgemm<<<dim3(F3/64, N_NODES/64), 256, 0, stream>>>(
        h, w_w2h + (size_t)l*F*F3, w_w2l + (size_t)l*F*F3,
        c_b2 + (size_t)l*F3, vin, nullptr, N_NODES, F3, F, 0);
    k_apply<<<NF/256, 256, 0, stream>>>(vin, dotb, UVv, s, vout, v_pk);
  }

  k_pack<<<NF/256, 256, 0, stream>>>(s, vB, (float*)d_out);
}